// Round 9
// baseline (100.772 us; speedup 1.0000x reference)
//
#include <hip/hip_runtime.h>
#include <stdint.h>

#define NB   8
#define NPTS 8192
#define NS   1024
#define NK   16
#define NH   192
#define KP1  224   // extended K for gemm1: 192 embed + 3 coords + 1 bias + 28 zero pad
#define HROW 236   // LDS row stride in bf16 elems; 118 dw = 22 mod 32 -> conflict-free 16-row reads
#define QTR  2048  // points per knn quarter-block
#define MR   64    // rows per mlp block (4 supernodes) -> 30.2KB LDS -> 4 blocks/CU

typedef float    f32x4 __attribute__((ext_vector_type(4)));
typedef short    s16x8 __attribute__((ext_vector_type(8)));
typedef uint32_t u32;
typedef unsigned long long u64;

// omega_m = 10000^(-m/32) = 10^(-m/8); constexpr so literal indexing folds at compile time
constexpr float OMEGA[32] = {
  1.0f, 0.74989420933245585f, 0.56234132519034907f, 0.42169650342858223f,
  0.31622776601683794f, 0.23713737056616552f, 0.17782794100389229f, 0.13335214321633237f,
  0.1f, 0.074989420933245585f, 0.056234132519034907f, 0.042169650342858223f,
  0.031622776601683794f, 0.023713737056616552f, 0.017782794100389229f, 0.013335214321633237f,
  0.01f, 0.0074989420933245585f, 0.0056234132519034907f, 0.0042169650342858223f,
  0.0031622776601683794f, 0.0023713737056616552f, 0.0017782794100389229f, 0.0013335214321633237f,
  0.001f, 0.00074989420933245585f, 0.00056234132519034907f, 0.00042169650342858223f,
  0.00031622776601683794f, 0.00023713737056616552f, 0.00017782794100389229f, 0.00013335214321633237f };

// exact RNE f32->bf16 (prep kernel only)
__device__ __forceinline__ uint16_t f2bf(float f) {
  u32 u = __float_as_uint(f);
  return (uint16_t)((u + 0x7FFFu + ((u >> 16) & 1u)) >> 16);
}
// fast pack of two f32 -> 2xbf16, round-half-up (0.5ulp; ref is f32)
__device__ __forceinline__ u32 pk2bf(float f0, float f1) {
  return ((__float_as_uint(f0) + 0x8000u) >> 16) |
         ((__float_as_uint(f1) + 0x8000u) & 0xFFFF0000u);
}

// ---------------- kernel A: build extended transposed weights ----------------
__global__ void __launch_bounds__(64) prep_weights(
    const float* __restrict__ w_in, const float* __restrict__ b_in,
    const float* __restrict__ w1, const float* __restrict__ b1,
    const float* __restrict__ w2,
    uint16_t* __restrict__ wT1e, uint16_t* __restrict__ wT2) {
  const int n = blockIdx.x, t = threadIdx.x;
  float p0 = 0, p1 = 0, p2 = 0, pb = 0;
  #pragma unroll
  for (int kk = 0; kk < 3; ++kk) {
    int c = kk * 64 + t;
    float w1cn = w1[c * NH + n];
    wT1e[n * KP1 + c] = f2bf(w1cn);
    wT2 [n * NH  + c] = f2bf(w2[c * NH + n]);
    p0 = fmaf(w_in[0 * NH + c], w1cn, p0);
    p1 = fmaf(w_in[1 * NH + c], w1cn, p1);
    p2 = fmaf(w_in[2 * NH + c], w1cn, p2);
    pb = fmaf(b_in[c], w1cn, pb);
  }
  #pragma unroll
  for (int off = 32; off; off >>= 1) {
    p0 += __shfl_down(p0, off);
    p1 += __shfl_down(p1, off);
    p2 += __shfl_down(p2, off);
    pb += __shfl_down(pb, off);
  }
  if (t == 0) {
    wT1e[n * KP1 + 192] = f2bf(p0);
    wT1e[n * KP1 + 193] = f2bf(p1);
    wT1e[n * KP1 + 194] = f2bf(p2);
    wT1e[n * KP1 + 195] = f2bf(pb + b1[n]);
  }
  if (t >= 4 && t < 32) wT1e[n * KP1 + 192 + t] = 0;
}

// ---------------- kernel B: exact top-16 over a QUARTER of the points ----------------
// r8 post-mortem: manual prefetch REGRESSED 40->52us (defeated compiler pipelining,
// common-mistake #5). This is the r7 form: plain loops, compiler schedules loads.
__global__ void __launch_bounds__(512, 8) knn_kernel(const float* __restrict__ pts,
                                                     const int* __restrict__ sidx,
                                                     u64* __restrict__ keys) {
  __shared__ float2 XY[QTR];   // 16 KB
  __shared__ float  Zs[QTR];   //  8 KB
  const int bid = blockIdx.x;
  const int b = bid >> 7;
  const int chunk = (bid >> 2) & 31;
  const int quarter = bid & 3;
  const int pbase = quarter * QTR;
  const float* pb = pts + ((size_t)b * NPTS + pbase) * 3;
  for (int i = threadIdx.x; i < QTR; i += 512) {
    XY[i] = float2{pb[3 * i], pb[3 * i + 1]};
    Zs[i] = pb[3 * i + 2];
  }
  __syncthreads();
  const int wave = threadIdx.x >> 6, lane = threadIdx.x & 63;
  const int sbase = chunk * 32 + wave * 4;

  float sx[4], sy[4], sz[4], minD[4], Td[4];
  u32 minI[4];
  u64 arr[4], T[4];
  #pragma unroll
  for (int q = 0; q < 4; ++q) {
    int si = sidx[b * NS + sbase + q];
    const float* qp = pts + ((size_t)b * NPTS + si) * 3;   // L2 broadcast
    sx[q] = qp[0]; sy[q] = qp[1]; sz[q] = qp[2];
    minD[q] = __uint_as_float(0x7F800000u);
    minI[q] = 0xFFFFFFFFu;
  }

  // ---- pass 1: lane-private minimum of each lane's 32-candidate column
  for (int t = 0; t < QTR / 64; ++t) {
    int lj = t * 64 + lane;
    float2 xy = XY[lj];
    float z = Zs[lj];
    #pragma unroll
    for (int q = 0; q < 4; ++q) {
      float dx = xy.x - sx[q], dy = xy.y - sy[q], dz = z - sz[q];
      float d = __fadd_rn(__fadd_rn(__fmul_rn(dx, dx), __fmul_rn(dy, dy)),
                          __fmul_rn(dz, dz));
      bool c = d < minD[q];            // strict: keeps lowest idx on exact ties
      minD[q] = c ? d : minD[q];
      minI[q] = c ? (u32)(pbase + lj) : minI[q];
    }
  }

  // ---- bitonic sort of the 64 per-lane minima (ascending across lanes)
  #pragma unroll
  for (int q = 0; q < 4; ++q) {
    u64 key = ((u64)__float_as_uint(minD[q]) << 32) | minI[q];
    #pragma unroll
    for (int k = 2; k <= 64; k <<= 1) {
      #pragma unroll
      for (int jj = k >> 1; jj > 0; jj >>= 1) {
        u64 p = __shfl_xor(key, jj);
        bool takeMin = (((lane & jj) == 0) == ((lane & k) == 0));
        key = (takeMin == (p < key)) ? p : key;
      }
    }
    arr[q] = (lane < 16) ? key : ~0ull;
    T[q] = __shfl(key, 15);                       // upper bound on true 16th key
    Td[q] = __uint_as_float((u32)(T[q] >> 32));
  }

  // ---- pass 2: exact insertion of the few candidates below the threshold
  for (int t = 0; t < QTR / 64; ++t) {
    int lj = t * 64 + lane;
    float2 xy = XY[lj];
    float z = Zs[lj];
    #pragma unroll
    for (int q = 0; q < 4; ++q) {
      float dx = xy.x - sx[q], dy = xy.y - sy[q], dz = z - sz[q];
      float d = __fadd_rn(__fadd_rn(__fmul_rn(dx, dx), __fmul_rn(dy, dy)),
                          __fmul_rn(dz, dz));
      u64 ball = __ballot(d <= Td[q] && (u32)(pbase + lj) != minI[q]);
      if (ball) {                                 // wave-uniform, rare
        u64 key = ((u64)__float_as_uint(d) << 32) | (u32)(pbase + lj);
        do {
          int src = __builtin_ctzll(ball);
          ball &= ball - 1;
          u64 k2 = __shfl(key, src);
          if (k2 < T[q]) {                        // exact (dist,idx) compare
            int r = __popcll(__ballot(arr[q] < k2));
            u64 up = __shfl_up(arr[q], 1);
            if (lane == r) arr[q] = k2;
            else if (lane > r && lane < 16) arr[q] = up;
            T[q] = __shfl(arr[q], 15);
            Td[q] = __uint_as_float((u32)(T[q] >> 32));
          }
        } while (ball);
      }
    }
  }
  #pragma unroll
  for (int q = 0; q < 4; ++q)
    if (lane < 16)
      keys[((size_t)(b * NS + sbase + q)) * 64 + quarter * 16 + lane] = arr[q];
}

// ---------------- kernel C: merge + gather + embed + MLP + mean-pool ----------------
// 64-row blocks (4 supernodes): 30.2KB LDS -> 4 blocks/CU (VGPR-capped) -> 4 waves/SIMD,
// 2x occupancy of r8 to hide per-kk L2 weight-fragment latency.
__device__ __forceinline__ float h0ch(int c, float c0, float c1, float c2) {
  if (c >= 196) return 0.0f;
  if (c == 195) return 1.0f;          // bias channel
  if (c == 192) return c0;
  if (c == 193) return c1;
  if (c == 194) return c2;
  int dd = c >> 6, i = c & 63, m = i & 31;
  float coord = (dd == 0) ? c0 : ((dd == 1) ? c1 : c2);
  float arg = coord * OMEGA[m];
  return (i < 32) ? __sinf(arg) : __cosf(arg);
}

__device__ __forceinline__ float gelu_f(float x) {
  float v = -1.5957691216057308f * __fmaf_rn(0.044715f * x, x * x, x);
  return x * __builtin_amdgcn_rcpf(1.0f + __expf(v));
}

__global__ void __launch_bounds__(256) mlp_kernel(
    const float* __restrict__ pts, const u64* __restrict__ keys,
    const float* __restrict__ b2v,
    const uint16_t* __restrict__ wT1e, const uint16_t* __restrict__ wT2,
    float* __restrict__ out) {
  __shared__ uint16_t hbuf[MR * HROW];   // 30.2 KB
  __shared__ int nbrL[MR];
  const int g = blockIdx.x, tid = threadIdx.x;
  const int wave = tid >> 6, lane = tid & 63;
  const int lrow = lane & 15, lg = lane >> 4;

  { // merge 4 sorted 16-lists for this wave's query (q = wave, 4 queries/block):
    // lists 1,3 loaded reversed -> two bitonic 32-merges (lanes<32 asc, >=32 desc)
    // -> one 64-merge asc. Keys globally unique.
    int list = lane >> 4, pos = lane & 15;
    int rpos = (list & 1) ? (15 - pos) : pos;
    u64 key = keys[((size_t)g * 4 + wave) * 64 + list * 16 + rpos];
    #pragma unroll
    for (int jj = 16; jj > 0; jj >>= 1) {
      u64 p = __shfl_xor(key, jj);
      bool takeMin = (((lane & jj) == 0) == ((lane & 32) == 0));
      key = (takeMin == (p < key)) ? p : key;
    }
    #pragma unroll
    for (int jj = 32; jj > 0; jj >>= 1) {
      u64 p = __shfl_xor(key, jj);
      bool takeMin = ((lane & jj) == 0);
      key = (takeMin == (p < key)) ? p : key;
    }
    if (lane < 16) nbrL[wave * 16 + lane] = (int)(u32)key;
  }
  __syncthreads();

  { // h0 fill: 4 threads/row, 56 channels each, four fully-static quarter-loops
    int r = tid >> 2, qt = tid & 3;
    int grow = g * MR + r;
    int b = grow >> 14;                        // / (NS*NK)
    int pidx = nbrL[r];
    const float* pp = pts + ((size_t)b * NPTS + pidx) * 3;
    float c0 = pp[0], c1 = pp[1], c2 = pp[2];
    uint16_t* hrow = hbuf + r * HROW;
    if (qt == 0) {
      #pragma unroll
      for (int jj = 0; jj < 14; ++jj) {
        const int c = jj * 4;
        uint2 pk;
        pk.x = pk2bf(h0ch(c,     c0, c1, c2), h0ch(c + 1, c0, c1, c2));
        pk.y = pk2bf(h0ch(c + 2, c0, c1, c2), h0ch(c + 3, c0, c1, c2));
        *(uint2*)(hrow + c) = pk;
      }
    } else if (qt == 1) {
      #pragma unroll
      for (int jj = 0; jj < 14; ++jj) {
        const int c = 56 + jj * 4;
        uint2 pk;
        pk.x = pk2bf(h0ch(c,     c0, c1, c2), h0ch(c + 1, c0, c1, c2));
        pk.y = pk2bf(h0ch(c + 2, c0, c1, c2), h0ch(c + 3, c0, c1, c2));
        *(uint2*)(hrow + c) = pk;
      }
    } else if (qt == 2) {
      #pragma unroll
      for (int jj = 0; jj < 14; ++jj) {
        const int c = 112 + jj * 4;
        uint2 pk;
        pk.x = pk2bf(h0ch(c,     c0, c1, c2), h0ch(c + 1, c0, c1, c2));
        pk.y = pk2bf(h0ch(c + 2, c0, c1, c2), h0ch(c + 3, c0, c1, c2));
        *(uint2*)(hrow + c) = pk;
      }
    } else {
      #pragma unroll
      for (int jj = 0; jj < 14; ++jj) {
        const int c = 168 + jj * 4;
        uint2 pk;
        pk.x = pk2bf(h0ch(c,     c0, c1, c2), h0ch(c + 1, c0, c1, c2));
        pk.y = pk2bf(h0ch(c + 2, c0, c1, c2), h0ch(c + 3, c0, c1, c2));
        *(uint2*)(hrow + c) = pk;
      }
    }
  }
  __syncthreads();

  // ---- gemm1 (SWAPPED operands): D1^T = wT1e-as-A x h0-as-B
  f32x4 acc1[3][4] = {};
  {
    const uint16_t* wbase = wT1e + (size_t)(wave * 48 + lrow) * KP1 + lg * 8;
    uint4 anx[3];
    #pragma unroll
    for (int nt = 0; nt < 3; ++nt) anx[nt] = *(const uint4*)(wbase + nt * 16 * KP1);
    #pragma unroll
    for (int kk = 0; kk < 7; ++kk) {
      uint4 acur[3];
      #pragma unroll
      for (int nt = 0; nt < 3; ++nt) acur[nt] = anx[nt];
      if (kk < 6) {
        #pragma unroll
        for (int nt = 0; nt < 3; ++nt)
          anx[nt] = *(const uint4*)(wbase + nt * 16 * KP1 + (kk + 1) * 32);
      }
      s16x8 bm[4];
      #pragma unroll
      for (int mt = 0; mt < 4; ++mt)
        bm[mt] = __builtin_bit_cast(s16x8,
                   *(const uint4*)(hbuf + (mt * 16 + lrow) * HROW + kk * 32 + lg * 8));
      #pragma unroll
      for (int nt = 0; nt < 3; ++nt)
        #pragma unroll
        for (int mt = 0; mt < 4; ++mt)
          acc1[nt][mt] = __builtin_amdgcn_mfma_f32_16x16x32_bf16(
              __builtin_bit_cast(s16x8, acur[nt]), bm[mt], acc1[nt][mt], 0, 0, 0);
    }
  }
  __syncthreads();   // all gemm1 reads of hbuf done before h1 overwrite

  { // epilogue 1: gelu (b1 folded), h1 write: 4 consecutive cols per b64 store
    #pragma unroll
    for (int nt = 0; nt < 3; ++nt) {
      #pragma unroll
      for (int mt = 0; mt < 4; ++mt) {
        uint2 pk;
        pk.x = pk2bf(gelu_f(acc1[nt][mt][0]), gelu_f(acc1[nt][mt][1]));
        pk.y = pk2bf(gelu_f(acc1[nt][mt][2]), gelu_f(acc1[nt][mt][3]));
        *(uint2*)(hbuf + (mt * 16 + lrow) * HROW + wave * 48 + nt * 16 + lg * 4) = pk;
      }
    }
  }
  __syncthreads();

  // ---- gemm2 (normal orientation): D2 = h1-as-A x wT2-as-B
  f32x4 acc2[4][3] = {};
  {
    const uint16_t* w2base = wT2 + (size_t)(wave * 48 + lrow) * NH + lg * 8;
    uint4 bnx[3];
    #pragma unroll
    for (int nt = 0; nt < 3; ++nt) bnx[nt] = *(const uint4*)(w2base + nt * 16 * NH);
    #pragma unroll
    for (int kk = 0; kk < 6; ++kk) {
      uint4 bcur[3];
      #pragma unroll
      for (int nt = 0; nt < 3; ++nt) bcur[nt] = bnx[nt];
      if (kk < 5) {
        #pragma unroll
        for (int nt = 0; nt < 3; ++nt)
          bnx[nt] = *(const uint4*)(w2base + nt * 16 * NH + (kk + 1) * 32);
      }
      s16x8 am[4];
      #pragma unroll
      for (int mt = 0; mt < 4; ++mt)
        am[mt] = __builtin_bit_cast(s16x8,
                   *(const uint4*)(hbuf + (mt * 16 + lrow) * HROW + kk * 32 + lg * 8));
      #pragma unroll
      for (int mt = 0; mt < 4; ++mt)
        #pragma unroll
        for (int nt = 0; nt < 3; ++nt)
          acc2[mt][nt] = __builtin_amdgcn_mfma_f32_16x16x32_bf16(
              am[mt], __builtin_bit_cast(s16x8, bcur[nt]), acc2[mt][nt], 0, 0, 0);
    }
  }

  { // epilogue 2: mean over 16 rows of each C-tile (one supernode) + b2
    #pragma unroll
    for (int mt = 0; mt < 4; ++mt) {
      #pragma unroll
      for (int nt = 0; nt < 3; ++nt) {
        float ssum = acc2[mt][nt][0] + acc2[mt][nt][1] + acc2[mt][nt][2] + acc2[mt][nt][3];
        ssum += __shfl_xor(ssum, 16);
        ssum += __shfl_xor(ssum, 32);
        if (lane < 16) {
          int col = wave * 48 + nt * 16 + lrow;
          out[(size_t)(g * 4 + mt) * NH + col] = ssum * 0.0625f + b2v[col];
        }
      }
    }
  }
}

extern "C" void kernel_launch(void* const* d_in, const int* in_sizes, int n_in,
                              void* d_out, int out_size, void* d_ws, size_t ws_size,
                              hipStream_t stream) {
  (void)in_sizes; (void)n_in; (void)out_size; (void)ws_size;
  const float* pts  = (const float*)d_in[0];
  const int*   sidx = (const int*)d_in[1];
  const float* w_in = (const float*)d_in[2];
  const float* b_in = (const float*)d_in[3];
  const float* w1   = (const float*)d_in[4];
  const float* b1   = (const float*)d_in[5];
  const float* w2   = (const float*)d_in[6];
  const float* b2   = (const float*)d_in[7];
  float* out = (float*)d_out;

  u64* keys = (u64*)d_ws;                                       // 8192*64*8 = 4 MB
  uint16_t* wT1e = (uint16_t*)((char*)d_ws + (size_t)NB * NS * 64 * 8);
  uint16_t* wT2  = wT1e + NH * KP1;

  hipLaunchKernelGGL(prep_weights, dim3(NH), dim3(64), 0, stream,
                     w_in, b_in, w1, b1, w2, wT1e, wT2);

  hipLaunchKernelGGL(knn_kernel, dim3(NB * 128), dim3(512), 0, stream,
                     pts, sidx, keys);

  hipLaunchKernelGGL(mlp_kernel, dim3(NB * NS / 4), dim3(256), 0, stream,
                     pts, keys, b2, wT1e, wT2, out);
}

// Round 10
// 100.692 us; speedup vs baseline: 1.0008x; 1.0008x over previous
//
#include <hip/hip_runtime.h>
#include <stdint.h>

#define NB   8
#define NPTS 8192
#define NS   1024
#define NK   16
#define NH   192
#define KP1  224   // extended K for gemm1: 192 embed + 3 coords + 1 bias + 28 zero pad
#define HROW 236   // LDS row stride in bf16 elems; conflict-free 16-row b128 reads
#define QTR  2048  // points per knn quarter-block
#define MR   128   // rows per mlp block (8 supernodes)

typedef float    f32x2 __attribute__((ext_vector_type(2)));
typedef float    f32x4 __attribute__((ext_vector_type(4)));
typedef short    s16x8 __attribute__((ext_vector_type(8)));
typedef uint32_t u32;
typedef unsigned long long u64;

constexpr float OMEGA[32] = {
  1.0f, 0.74989420933245585f, 0.56234132519034907f, 0.42169650342858223f,
  0.31622776601683794f, 0.23713737056616552f, 0.17782794100389229f, 0.13335214321633237f,
  0.1f, 0.074989420933245585f, 0.056234132519034907f, 0.042169650342858223f,
  0.031622776601683794f, 0.023713737056616552f, 0.017782794100389229f, 0.013335214321633237f,
  0.01f, 0.0074989420933245585f, 0.0056234132519034907f, 0.0042169650342858223f,
  0.0031622776601683794f, 0.0023713737056616552f, 0.0017782794100389229f, 0.0013335214321633237f,
  0.001f, 0.00074989420933245585f, 0.00056234132519034907f, 0.00042169650342858223f,
  0.00031622776601683794f, 0.00023713737056616552f, 0.00017782794100389229f, 0.00013335214321633237f };

__device__ __forceinline__ uint16_t f2bf(float f) {
  u32 u = __float_as_uint(f);
  return (uint16_t)((u + 0x7FFFu + ((u >> 16) & 1u)) >> 16);
}
__device__ __forceinline__ u32 pk2bf(float f0, float f1) {
  return ((__float_as_uint(f0) + 0x8000u) >> 16) |
         ((__float_as_uint(f1) + 0x8000u) & 0xFFFF0000u);
}

// ---------------- kernel A: build extended transposed weights ----------------
__global__ void __launch_bounds__(64) prep_weights(
    const float* __restrict__ w_in, const float* __restrict__ b_in,
    const float* __restrict__ w1, const float* __restrict__ b1,
    const float* __restrict__ w2,
    uint16_t* __restrict__ wT1e, uint16_t* __restrict__ wT2) {
  const int n = blockIdx.x, t = threadIdx.x;
  float p0 = 0, p1 = 0, p2 = 0, pb = 0;
  #pragma unroll
  for (int kk = 0; kk < 3; ++kk) {
    int c = kk * 64 + t;
    float w1cn = w1[c * NH + n];
    wT1e[n * KP1 + c] = f2bf(w1cn);
    wT2 [n * NH  + c] = f2bf(w2[c * NH + n]);
    p0 = fmaf(w_in[0 * NH + c], w1cn, p0);
    p1 = fmaf(w_in[1 * NH + c], w1cn, p1);
    p2 = fmaf(w_in[2 * NH + c], w1cn, p2);
    pb = fmaf(b_in[c], w1cn, pb);
  }
  #pragma unroll
  for (int off = 32; off; off >>= 1) {
    p0 += __shfl_down(p0, off);
    p1 += __shfl_down(p1, off);
    p2 += __shfl_down(p2, off);
    pb += __shfl_down(pb, off);
  }
  if (t == 0) {
    wT1e[n * KP1 + 192] = f2bf(p0);
    wT1e[n * KP1 + 193] = f2bf(p1);
    wT1e[n * KP1 + 194] = f2bf(p2);
    wT1e[n * KP1 + 195] = f2bf(pb + b1[n]);
  }
  if (t >= 4 && t < 32) wT1e[n * KP1 + 192 + t] = 0;
}

// ---------------- kernel B: exact top-16, packed-f32 two-pass ----------------
// Pair-SoA LDS; each lane evaluates 2 candidates per pk_mul/pk_add (contract(off)
// keeps the exact mul,mul,mul,add,add rounding; packed halves are IEEE-identical
// to scalar). Pass 1 tracks per-half (minD,minI); combined min enters the bitonic
// sort. Pass 2: the non-winning half-min is NOT excluded (it never sorted) —
// exclusion is combined-winner only; each half inserts exactly.
__global__ void __launch_bounds__(512, 4) knn_kernel(const float* __restrict__ pts,
                                                     const int* __restrict__ sidx,
                                                     u64* __restrict__ keys) {
  #pragma clang fp contract(off)
  __shared__ f32x2 Xp[QTR / 2];   // 8 KB  (x of candidates 2i, 2i+1)
  __shared__ f32x2 Yp[QTR / 2];   // 8 KB
  __shared__ f32x2 Zp[QTR / 2];   // 8 KB
  const int bid = blockIdx.x;
  const int b = bid >> 7;
  const int chunk = (bid >> 2) & 31;
  const int quarter = bid & 3;
  const int pbase = quarter * QTR;
  const float* pb = pts + ((size_t)b * NPTS + pbase) * 3;
  for (int i = threadIdx.x; i < QTR; i += 512) {
    ((float*)Xp)[i] = pb[3 * i + 0];
    ((float*)Yp)[i] = pb[3 * i + 1];
    ((float*)Zp)[i] = pb[3 * i + 2];
  }
  __syncthreads();
  const int wave = threadIdx.x >> 6, lane = threadIdx.x & 63;
  const int sbase = chunk * 32 + wave * 4;

  f32x2 sx2[4], sy2[4], sz2[4];
  float mnDx[4], mnDy[4], Td[4];
  u32 mnI0[4], mnI1[4], minI[4];
  u64 arr[4], T[4];
  #pragma unroll
  for (int q = 0; q < 4; ++q) {
    int si = sidx[b * NS + sbase + q];
    const float* qp = pts + ((size_t)b * NPTS + si) * 3;   // L2 broadcast
    sx2[q] = f32x2{qp[0], qp[0]};
    sy2[q] = f32x2{qp[1], qp[1]};
    sz2[q] = f32x2{qp[2], qp[2]};
    mnDx[q] = __uint_as_float(0x7F800000u);
    mnDy[q] = __uint_as_float(0x7F800000u);
    mnI0[q] = 0xFFFFFFFFu; mnI1[q] = 0xFFFFFFFFu;
  }

  // ---- pass 1: per-half lane-private minima, 2 candidates per packed op
  for (int t = 0; t < QTR / 128; ++t) {
    int lp = t * 64 + lane;
    f32x2 xs = Xp[lp], ys = Yp[lp], zs = Zp[lp];
    u32 j0 = (u32)(pbase + 2 * lp);
    #pragma unroll
    for (int q = 0; q < 4; ++q) {
      f32x2 dx = xs - sx2[q], dy = ys - sy2[q], dz = zs - sz2[q];
      f32x2 d = ((dx * dx) + (dy * dy)) + (dz * dz);
      bool c0 = d.x < mnDx[q];             // strict: lowest idx on exact ties
      mnDx[q] = c0 ? d.x : mnDx[q];
      mnI0[q] = c0 ? j0 : mnI0[q];
      bool c1 = d.y < mnDy[q];
      mnDy[q] = c1 ? d.y : mnDy[q];
      mnI1[q] = c1 ? (j0 + 1) : mnI1[q];
    }
  }

  // ---- combine halves, bitonic sort of the 64 combined minima
  #pragma unroll
  for (int q = 0; q < 4; ++q) {
    u64 k0 = ((u64)__float_as_uint(mnDx[q]) << 32) | mnI0[q];
    u64 k1 = ((u64)__float_as_uint(mnDy[q]) << 32) | mnI1[q];
    u64 key = (k0 < k1) ? k0 : k1;
    minI[q] = (u32)key;                    // combined winner (pass-2 exclusion)
    #pragma unroll
    for (int k = 2; k <= 64; k <<= 1) {
      #pragma unroll
      for (int jj = k >> 1; jj > 0; jj >>= 1) {
        u64 p = __shfl_xor(key, jj);
        bool takeMin = (((lane & jj) == 0) == ((lane & k) == 0));
        key = (takeMin == (p < key)) ? p : key;
      }
    }
    arr[q] = (lane < 16) ? key : ~0ull;
    T[q] = __shfl(key, 15);
    Td[q] = __uint_as_float((u32)(T[q] >> 32));
  }

  // ---- pass 2: exact insertion of candidates below the threshold
  for (int t = 0; t < QTR / 128; ++t) {
    int lp = t * 64 + lane;
    f32x2 xs = Xp[lp], ys = Yp[lp], zs = Zp[lp];
    u32 j0 = (u32)(pbase + 2 * lp);
    #pragma unroll
    for (int q = 0; q < 4; ++q) {
      f32x2 dx = xs - sx2[q], dy = ys - sy2[q], dz = zs - sz2[q];
      f32x2 d = ((dx * dx) + (dy * dy)) + (dz * dz);
      bool c0 = (d.x <= Td[q]) && (j0 != minI[q]);
      bool c1 = (d.y <= Td[q]) && ((j0 + 1) != minI[q]);
      u64 gate = __ballot(c0 || c1);
      if (gate) {                                 // wave-uniform, rare
        u64 b0 = __ballot(c0);
        u64 key0 = ((u64)__float_as_uint(d.x) << 32) | j0;
        while (b0) {
          int src = __builtin_ctzll(b0);
          b0 &= b0 - 1;
          u64 k2 = __shfl(key0, src);
          if (k2 < T[q]) {
            int r = __popcll(__ballot(arr[q] < k2));
            u64 up = __shfl_up(arr[q], 1);
            if (lane == r) arr[q] = k2;
            else if (lane > r && lane < 16) arr[q] = up;
            T[q] = __shfl(arr[q], 15);
            Td[q] = __uint_as_float((u32)(T[q] >> 32));
          }
        }
        u64 b1 = __ballot(c1);
        u64 key1 = ((u64)__float_as_uint(d.y) << 32) | (j0 + 1);
        while (b1) {
          int src = __builtin_ctzll(b1);
          b1 &= b1 - 1;
          u64 k2 = __shfl(key1, src);
          if (k2 < T[q]) {
            int r = __popcll(__ballot(arr[q] < k2));
            u64 up = __shfl_up(arr[q], 1);
            if (lane == r) arr[q] = k2;
            else if (lane > r && lane < 16) arr[q] = up;
            T[q] = __shfl(arr[q], 15);
            Td[q] = __uint_as_float((u32)(T[q] >> 32));
          }
        }
      }
    }
  }
  #pragma unroll
  for (int q = 0; q < 4; ++q)
    if (lane < 16)
      keys[((size_t)(b * NS + sbase + q)) * 64 + quarter * 16 + lane] = arr[q];
}

// ---------------- kernel C: merge + gather + embed + MLP + mean-pool ----------------
// MR=128 (r8 geometry: best weight amortization) but 8 waves/block: wave =
// (m-half, n-slice) -> same LDS, 2x waves -> 4 waves/SIMD.
__device__ __forceinline__ float h0ch(int c, float c0, float c1, float c2) {
  if (c >= 196) return 0.0f;
  if (c == 195) return 1.0f;
  if (c == 192) return c0;
  if (c == 193) return c1;
  if (c == 194) return c2;
  int dd = c >> 6, i = c & 63, m = i & 31;
  float coord = (dd == 0) ? c0 : ((dd == 1) ? c1 : c2);
  float arg = coord * OMEGA[m];
  return (i < 32) ? __sinf(arg) : __cosf(arg);
}

__device__ __forceinline__ float gelu_f(float x) {
  float v = -1.5957691216057308f * __fmaf_rn(0.044715f * x, x * x, x);
  return x * __builtin_amdgcn_rcpf(1.0f + __expf(v));
}

__global__ void __launch_bounds__(512, 4) mlp_kernel(
    const float* __restrict__ pts, const u64* __restrict__ keys,
    const float* __restrict__ b2v,
    const uint16_t* __restrict__ wT1e, const uint16_t* __restrict__ wT2,
    float* __restrict__ out) {
  __shared__ uint16_t hbuf[MR * HROW];   // 60.4 KB -> 2 blocks/CU, 16 waves/CU
  __shared__ int nbrL[MR];
  const int g = blockIdx.x, tid = threadIdx.x;
  const int wave = tid >> 6, lane = tid & 63;
  const int lrow = lane & 15, lg = lane >> 4;
  const int mh = wave >> 2;              // m-half (0..1): rows mh*64..+64
  const int ns = wave & 3;               // n-slice (0..3): cols ns*48..+48

  { // merge 4 sorted 16-lists for query (g*8 + wave)
    int list = lane >> 4, pos = lane & 15;
    int rpos = (list & 1) ? (15 - pos) : pos;
    u64 key = keys[((size_t)g * 8 + wave) * 64 + list * 16 + rpos];
    #pragma unroll
    for (int jj = 16; jj > 0; jj >>= 1) {
      u64 p = __shfl_xor(key, jj);
      bool takeMin = (((lane & jj) == 0) == ((lane & 32) == 0));
      key = (takeMin == (p < key)) ? p : key;
    }
    #pragma unroll
    for (int jj = 32; jj > 0; jj >>= 1) {
      u64 p = __shfl_xor(key, jj);
      bool takeMin = ((lane & jj) == 0);
      key = (takeMin == (p < key)) ? p : key;
    }
    if (lane < 16) nbrL[wave * 16 + lane] = (int)(u32)key;
  }
  __syncthreads();

  { // h0 fill: 4 threads/row, four fully-static quarter-loops (c literal)
    int r = tid >> 2, qt = tid & 3;
    int grow = g * MR + r;
    int b = grow >> 14;
    int pidx = nbrL[r];
    const float* pp = pts + ((size_t)b * NPTS + pidx) * 3;
    float c0 = pp[0], c1 = pp[1], c2 = pp[2];
    uint16_t* hrow = hbuf + r * HROW;
    if (qt == 0) {
      #pragma unroll
      for (int jj = 0; jj < 14; ++jj) {
        const int c = jj * 4;
        uint2 pk;
        pk.x = pk2bf(h0ch(c,     c0, c1, c2), h0ch(c + 1, c0, c1, c2));
        pk.y = pk2bf(h0ch(c + 2, c0, c1, c2), h0ch(c + 3, c0, c1, c2));
        *(uint2*)(hrow + c) = pk;
      }
    } else if (qt == 1) {
      #pragma unroll
      for (int jj = 0; jj < 14; ++jj) {
        const int c = 56 + jj * 4;
        uint2 pk;
        pk.x = pk2bf(h0ch(c,     c0, c1, c2), h0ch(c + 1, c0, c1, c2));
        pk.y = pk2bf(h0ch(c + 2, c0, c1, c2), h0ch(c + 3, c0, c1, c2));
        *(uint2*)(hrow + c) = pk;
      }
    } else if (qt == 2) {
      #pragma unroll
      for (int jj = 0; jj < 14; ++jj) {
        const int c = 112 + jj * 4;
        uint2 pk;
        pk.x = pk2bf(h0ch(c,     c0, c1, c2), h0ch(c + 1, c0, c1, c2));
        pk.y = pk2bf(h0ch(c + 2, c0, c1, c2), h0ch(c + 3, c0, c1, c2));
        *(uint2*)(hrow + c) = pk;
      }
    } else {
      #pragma unroll
      for (int jj = 0; jj < 14; ++jj) {
        const int c = 168 + jj * 4;
        uint2 pk;
        pk.x = pk2bf(h0ch(c,     c0, c1, c2), h0ch(c + 1, c0, c1, c2));
        pk.y = pk2bf(h0ch(c + 2, c0, c1, c2), h0ch(c + 3, c0, c1, c2));
        *(uint2*)(hrow + c) = pk;
      }
    }
  }
  __syncthreads();

  // ---- gemm1 (SWAPPED operands): D1^T = wT1e-as-A x h0-as-B
  f32x4 acc1[3][4] = {};
  {
    const uint16_t* wbase = wT1e + (size_t)(ns * 48 + lrow) * KP1 + lg * 8;
    uint4 anx[3];
    #pragma unroll
    for (int nt = 0; nt < 3; ++nt) anx[nt] = *(const uint4*)(wbase + nt * 16 * KP1);
    #pragma unroll
    for (int kk = 0; kk < 7; ++kk) {
      uint4 acur[3];
      #pragma unroll
      for (int nt = 0; nt < 3; ++nt) acur[nt] = anx[nt];
      if (kk < 6) {
        #pragma unroll
        for (int nt = 0; nt < 3; ++nt)
          anx[nt] = *(const uint4*)(wbase + nt * 16 * KP1 + (kk + 1) * 32);
      }
      s16x8 bm[4];
      #pragma unroll
      for (int mt = 0; mt < 4; ++mt)
        bm[mt] = __builtin_bit_cast(s16x8,
                   *(const uint4*)(hbuf + (mh * 64 + mt * 16 + lrow) * HROW + kk * 32 + lg * 8));
      #pragma unroll
      for (int nt = 0; nt < 3; ++nt)
        #pragma unroll
        for (int mt = 0; mt < 4; ++mt)
          acc1[nt][mt] = __builtin_amdgcn_mfma_f32_16x16x32_bf16(
              __builtin_bit_cast(s16x8, acur[nt]), bm[mt], acc1[nt][mt], 0, 0, 0);
    }
  }
  __syncthreads();   // all gemm1 reads of hbuf done before h1 overwrite

  { // epilogue 1: gelu (b1 folded), h1 write: 4 consecutive cols per b64 store
    #pragma unroll
    for (int nt = 0; nt < 3; ++nt) {
      #pragma unroll
      for (int mt = 0; mt < 4; ++mt) {
        uint2 pk;
        pk.x = pk2bf(gelu_f(acc1[nt][mt][0]), gelu_f(acc1[nt][mt][1]));
        pk.y = pk2bf(gelu_f(acc1[nt][mt][2]), gelu_f(acc1[nt][mt][3]));
        *(uint2*)(hbuf + (mh * 64 + mt * 16 + lrow) * HROW + ns * 48 + nt * 16 + lg * 4) = pk;
      }
    }
  }
  __syncthreads();

  // ---- gemm2 (normal orientation): D2 = h1-as-A x wT2-as-B
  f32x4 acc2[4][3] = {};
  {
    const uint16_t* w2base = wT2 + (size_t)(ns * 48 + lrow) * NH + lg * 8;
    uint4 bnx[3];
    #pragma unroll
    for (int nt = 0; nt < 3; ++nt) bnx[nt] = *(const uint4*)(w2base + nt * 16 * NH);
    #pragma unroll
    for (int kk = 0; kk < 6; ++kk) {
      uint4 bcur[3];
      #pragma unroll
      for (int nt = 0; nt < 3; ++nt) bcur[nt] = bnx[nt];
      if (kk < 5) {
        #pragma unroll
        for (int nt = 0; nt < 3; ++nt)
          bnx[nt] = *(const uint4*)(w2base + nt * 16 * NH + (kk + 1) * 32);
      }
      s16x8 am[4];
      #pragma unroll
      for (int mt = 0; mt < 4; ++mt)
        am[mt] = __builtin_bit_cast(s16x8,
                   *(const uint4*)(hbuf + (mh * 64 + mt * 16 + lrow) * HROW + kk * 32 + lg * 8));
      #pragma unroll
      for (int mt = 0; mt < 4; ++mt)
        #pragma unroll
        for (int nt = 0; nt < 3; ++nt)
          acc2[mt][nt] = __builtin_amdgcn_mfma_f32_16x16x32_bf16(
              am[mt], __builtin_bit_cast(s16x8, bcur[nt]), acc2[mt][nt], 0, 0, 0);
    }
  }

  { // epilogue 2: mean over 16 rows of each C-tile (one supernode) + b2
    #pragma unroll
    for (int mt = 0; mt < 4; ++mt) {
      #pragma unroll
      for (int nt = 0; nt < 3; ++nt) {
        float ssum = acc2[mt][nt][0] + acc2[mt][nt][1] + acc2[mt][nt][2] + acc2[mt][nt][3];
        ssum += __shfl_xor(ssum, 16);
        ssum += __shfl_xor(ssum, 32);
        if (lane < 16) {
          int col = ns * 48 + nt * 16 + lrow;
          out[(size_t)(g * 8 + mh * 4 + mt) * NH + col] = ssum * 0.0625f + b2v[col];
        }
      }
    }
  }
}

extern "C" void kernel_launch(void* const* d_in, const int* in_sizes, int n_in,
                              void* d_out, int out_size, void* d_ws, size_t ws_size,
                              hipStream_t stream) {
  (void)in_sizes; (void)n_in; (void)out_size; (void)ws_size;
  const float* pts  = (const float*)d_in[0];
  const int*   sidx = (const int*)d_in[1];
  const float* w_in = (const float*)d_in[2];
  const float* b_in = (const float*)d_in[3];
  const float* w1   = (const float*)d_in[4];
  const float* b1   = (const float*)d_in[5];
  const float* w2   = (const float*)d_in[6];
  const float* b2   = (const float*)d_in[7];
  float* out = (float*)d_out;

  u64* keys = (u64*)d_ws;                                       // 8192*64*8 = 4 MB
  uint16_t* wT1e = (uint16_t*)((char*)d_ws + (size_t)NB * NS * 64 * 8);
  uint16_t* wT2  = wT1e + NH * KP1;

  hipLaunchKernelGGL(prep_weights, dim3(NH), dim3(64), 0, stream,
                     w_in, b_in, w1, b1, w2, wT1e, wT2);

  hipLaunchKernelGGL(knn_kernel, dim3(NB * 128), dim3(512), 0, stream,
                     pts, sidx, keys);

  hipLaunchKernelGGL(mlp_kernel, dim3(NB * NS / 8), dim3(512), 0, stream,
                     pts, keys, b2, wT1e, wT2, out);
}

// Round 12
// 92.138 us; speedup vs baseline: 1.0937x; 1.0928x over previous
//
#include <hip/hip_runtime.h>
#include <stdint.h>

#define NB   8
#define NPTS 8192
#define NS   1024
#define NK   16
#define NH   192
#define KP1  224   // extended K for gemm1 weights: 192 + 3 coords + 1 bias + 28 zero pad
#define HROW 196   // hbuf row stride (bf16): 98 dw, gcd(98,32)=2 -> 16-distinct banks/16 rows
#define QTR  2048  // points per knn quarter-block

typedef float    f32x4 __attribute__((ext_vector_type(4)));
typedef short    s16x8 __attribute__((ext_vector_type(8)));
typedef uint32_t u32;
typedef unsigned long long u64;

constexpr float OMEGA[32] = {
  1.0f, 0.74989420933245585f, 0.56234132519034907f, 0.42169650342858223f,
  0.31622776601683794f, 0.23713737056616552f, 0.17782794100389229f, 0.13335214321633237f,
  0.1f, 0.074989420933245585f, 0.056234132519034907f, 0.042169650342858223f,
  0.031622776601683794f, 0.023713737056616552f, 0.017782794100389229f, 0.013335214321633237f,
  0.01f, 0.0074989420933245585f, 0.0056234132519034907f, 0.0042169650342858223f,
  0.0031622776601683794f, 0.0023713737056616552f, 0.0017782794100389229f, 0.0013335214321633237f,
  0.001f, 0.00074989420933245585f, 0.00056234132519034907f, 0.00042169650342858223f,
  0.00031622776601683794f, 0.00023713737056616552f, 0.00017782794100389229f, 0.00013335214321633237f };

__device__ __forceinline__ uint16_t f2bf(float f) {
  u32 u = __float_as_uint(f);
  return (uint16_t)((u + 0x7FFFu + ((u >> 16) & 1u)) >> 16);
}
__device__ __forceinline__ u32 pk2bf(float f0, float f1) {
  return ((__float_as_uint(f0) + 0x8000u) >> 16) |
         ((__float_as_uint(f1) + 0x8000u) & 0xFFFF0000u);
}

// ---------------- kernel A: build extended transposed weights ----------------
__global__ void __launch_bounds__(64) prep_weights(
    const float* __restrict__ w_in, const float* __restrict__ b_in,
    const float* __restrict__ w1, const float* __restrict__ b1,
    const float* __restrict__ w2,
    uint16_t* __restrict__ wT1e, uint16_t* __restrict__ wT2) {
  const int n = blockIdx.x, t = threadIdx.x;
  float p0 = 0, p1 = 0, p2 = 0, pb = 0;
  #pragma unroll
  for (int kk = 0; kk < 3; ++kk) {
    int c = kk * 64 + t;
    float w1cn = w1[c * NH + n];
    wT1e[n * KP1 + c] = f2bf(w1cn);
    wT2 [n * NH  + c] = f2bf(w2[c * NH + n]);
    p0 = fmaf(w_in[0 * NH + c], w1cn, p0);
    p1 = fmaf(w_in[1 * NH + c], w1cn, p1);
    p2 = fmaf(w_in[2 * NH + c], w1cn, p2);
    pb = fmaf(b_in[c], w1cn, pb);
  }
  #pragma unroll
  for (int off = 32; off; off >>= 1) {
    p0 += __shfl_down(p0, off);
    p1 += __shfl_down(p1, off);
    p2 += __shfl_down(p2, off);
    pb += __shfl_down(pb, off);
  }
  if (t == 0) {
    wT1e[n * KP1 + 192] = f2bf(p0);
    wT1e[n * KP1 + 193] = f2bf(p1);
    wT1e[n * KP1 + 194] = f2bf(p2);
    wT1e[n * KP1 + 195] = f2bf(pb + b1[n]);
  }
  if (t >= 4 && t < 32) wT1e[n * KP1 + 192 + t] = 0;
}

// ---------------- kernel B: exact top-16 over a QUARTER (r9 known-good form) ----------------
__global__ void __launch_bounds__(512, 8) knn_kernel(const float* __restrict__ pts,
                                                     const int* __restrict__ sidx,
                                                     u64* __restrict__ keys) {
  __shared__ float2 XY[QTR];   // 16 KB
  __shared__ float  Zs[QTR];   //  8 KB
  const int bid = blockIdx.x;
  const int b = bid >> 7;
  const int chunk = (bid >> 2) & 31;
  const int quarter = bid & 3;
  const int pbase = quarter * QTR;
  const float* pb = pts + ((size_t)b * NPTS + pbase) * 3;
  for (int i = threadIdx.x; i < QTR; i += 512) {
    XY[i] = float2{pb[3 * i], pb[3 * i + 1]};
    Zs[i] = pb[3 * i + 2];
  }
  __syncthreads();
  const int wave = threadIdx.x >> 6, lane = threadIdx.x & 63;
  const int sbase = chunk * 32 + wave * 4;

  float sx[4], sy[4], sz[4], minD[4], Td[4];
  u32 minI[4];
  u64 arr[4], T[4];
  #pragma unroll
  for (int q = 0; q < 4; ++q) {
    int si = sidx[b * NS + sbase + q];
    const float* qp = pts + ((size_t)b * NPTS + si) * 3;   // L2 broadcast
    sx[q] = qp[0]; sy[q] = qp[1]; sz[q] = qp[2];
    minD[q] = __uint_as_float(0x7F800000u);
    minI[q] = 0xFFFFFFFFu;
  }

  for (int t = 0; t < QTR / 64; ++t) {
    int lj = t * 64 + lane;
    float2 xy = XY[lj];
    float z = Zs[lj];
    #pragma unroll
    for (int q = 0; q < 4; ++q) {
      float dx = xy.x - sx[q], dy = xy.y - sy[q], dz = z - sz[q];
      float d = __fadd_rn(__fadd_rn(__fmul_rn(dx, dx), __fmul_rn(dy, dy)),
                          __fmul_rn(dz, dz));
      bool c = d < minD[q];            // strict: keeps lowest idx on exact ties
      minD[q] = c ? d : minD[q];
      minI[q] = c ? (u32)(pbase + lj) : minI[q];
    }
  }

  #pragma unroll
  for (int q = 0; q < 4; ++q) {
    u64 key = ((u64)__float_as_uint(minD[q]) << 32) | minI[q];
    #pragma unroll
    for (int k = 2; k <= 64; k <<= 1) {
      #pragma unroll
      for (int jj = k >> 1; jj > 0; jj >>= 1) {
        u64 p = __shfl_xor(key, jj);
        bool takeMin = (((lane & jj) == 0) == ((lane & k) == 0));
        key = (takeMin == (p < key)) ? p : key;
      }
    }
    arr[q] = (lane < 16) ? key : ~0ull;
    T[q] = __shfl(key, 15);
    Td[q] = __uint_as_float((u32)(T[q] >> 32));
  }

  for (int t = 0; t < QTR / 64; ++t) {
    int lj = t * 64 + lane;
    float2 xy = XY[lj];
    float z = Zs[lj];
    #pragma unroll
    for (int q = 0; q < 4; ++q) {
      float dx = xy.x - sx[q], dy = xy.y - sy[q], dz = z - sz[q];
      float d = __fadd_rn(__fadd_rn(__fmul_rn(dx, dx), __fmul_rn(dy, dy)),
                          __fmul_rn(dz, dz));
      u64 ball = __ballot(d <= Td[q] && (u32)(pbase + lj) != minI[q]);
      if (ball) {                                 // wave-uniform, rare
        u64 key = ((u64)__float_as_uint(d) << 32) | (u32)(pbase + lj);
        do {
          int src = __builtin_ctzll(ball);
          ball &= ball - 1;
          u64 k2 = __shfl(key, src);
          if (k2 < T[q]) {
            int r = __popcll(__ballot(arr[q] < k2));
            u64 up = __shfl_up(arr[q], 1);
            if (lane == r) arr[q] = k2;
            else if (lane > r && lane < 16) arr[q] = up;
            T[q] = __shfl(arr[q], 15);
            Td[q] = __uint_as_float((u32)(T[q] >> 32));
          }
        } while (ball);
      }
    }
  }
  #pragma unroll
  for (int q = 0; q < 4; ++q)
    if (lane < 16)
      keys[((size_t)(b * NS + sbase + q)) * 64 + quarter * 16 + lane] = arr[q];
}

// ---------------- kernel C: merge + gather + embed + MLP + mean-pool ----------------
// r8 geometry (4 waves = 4 n-slices, 8 m-tiles: weights touched ONCE per block) +
// HROW=196 via in-register kk6 B-fragment -> 52.2KB LDS -> 3 blocks/CU;
// 2-deep weight prefetch covers ~200cy L2 latency.
// r11 NaN bug: h0-fill used 4 thr/row with 256 threads -> rows 64..127 never
// written. Fixed: 2 threads/row (tid>>1), 96 channels each.
__device__ __forceinline__ float h0ch(int c, float c0, float c1, float c2) {
  int dd = c >> 6, i = c & 63, m = i & 31;
  float coord = (dd == 0) ? c0 : ((dd == 1) ? c1 : c2);
  float arg = coord * OMEGA[m];
  return (i < 32) ? __sinf(arg) : __cosf(arg);
}

__device__ __forceinline__ float gelu_f(float x) {
  float v = -1.5957691216057308f * __fmaf_rn(0.044715f * x, x * x, x);
  return x * __builtin_amdgcn_rcpf(1.0f + __expf(v));
}

__global__ void __launch_bounds__(256, 3) mlp_kernel(
    const float* __restrict__ pts, const u64* __restrict__ keys,
    const float* __restrict__ b2v,
    const uint16_t* __restrict__ wT1e, const uint16_t* __restrict__ wT2,
    float* __restrict__ out) {
  __shared__ uint16_t hbuf[128 * HROW];   // 50.2 KB
  __shared__ float crdL[128][3];          // 1.5 KB (coords per row, for kk6 frag)
  __shared__ int nbrL[128];               // 0.5 KB  -> total 52.2 KB: 3 blocks/CU
  const int g = blockIdx.x, tid = threadIdx.x;
  const int wave = tid >> 6, lane = tid & 63;
  const int lrow = lane & 15, lg = lane >> 4;
  const int ns = wave;                    // n-slice: cols ns*48..+48

  #pragma unroll
  for (int ii = 0; ii < 2; ++ii) { // merge 4 sorted 16-lists for query g*8 + ii*4 + wave
    int q = ii * 4 + wave;
    int list = lane >> 4, pos = lane & 15;
    int rpos = (list & 1) ? (15 - pos) : pos;
    u64 key = keys[((size_t)g * 8 + q) * 64 + list * 16 + rpos];
    #pragma unroll
    for (int jj = 16; jj > 0; jj >>= 1) {
      u64 p = __shfl_xor(key, jj);
      bool takeMin = (((lane & jj) == 0) == ((lane & 32) == 0));
      key = (takeMin == (p < key)) ? p : key;
    }
    #pragma unroll
    for (int jj = 32; jj > 0; jj >>= 1) {
      u64 p = __shfl_xor(key, jj);
      bool takeMin = ((lane & jj) == 0);
      key = (takeMin == (p < key)) ? p : key;
    }
    if (lane < 16) nbrL[q * 16 + lane] = (int)(u32)key;
  }
  __syncthreads();

  { // h0 fill (sincos channels 0..191), 2 threads/row, static half-loops
    int r = tid >> 1, half = tid & 1;
    int grow = g * 128 + r;
    int b = grow >> 14;
    int pidx = nbrL[r];
    const float* pp = pts + ((size_t)b * NPTS + pidx) * 3;
    float c0 = pp[0], c1 = pp[1], c2 = pp[2];
    uint16_t* hrow = hbuf + r * HROW;
    if (half == 0) {
      crdL[r][0] = c0; crdL[r][1] = c1; crdL[r][2] = c2;
      #pragma unroll
      for (int jj = 0; jj < 24; ++jj) {
        const int c = jj * 4;
        uint2 pk;
        pk.x = pk2bf(h0ch(c,     c0, c1, c2), h0ch(c + 1, c0, c1, c2));
        pk.y = pk2bf(h0ch(c + 2, c0, c1, c2), h0ch(c + 3, c0, c1, c2));
        *(uint2*)(hrow + c) = pk;
      }
    } else {
      #pragma unroll
      for (int jj = 0; jj < 24; ++jj) {
        const int c = 96 + jj * 4;
        uint2 pk;
        pk.x = pk2bf(h0ch(c,     c0, c1, c2), h0ch(c + 1, c0, c1, c2));
        pk.y = pk2bf(h0ch(c + 2, c0, c1, c2), h0ch(c + 3, c0, c1, c2));
        *(uint2*)(hrow + c) = pk;
      }
    }
  }
  __syncthreads();

  // ---- gemm1 (SWAPPED operands): D1^T = wT1e-as-A x h0-as-B; kk6 B built in-reg
  f32x4 acc1[3][8] = {};
  {
    const uint16_t* wbase = wT1e + (size_t)(ns * 48 + lrow) * KP1 + lg * 8;
    uint4 anx[2][3];
    #pragma unroll
    for (int nt = 0; nt < 3; ++nt) {
      anx[0][nt] = *(const uint4*)(wbase + nt * 16 * KP1);
      anx[1][nt] = *(const uint4*)(wbase + nt * 16 * KP1 + 32);
    }
    #pragma unroll
    for (int kk = 0; kk < 7; ++kk) {
      uint4 acur[3];
      #pragma unroll
      for (int nt = 0; nt < 3; ++nt) acur[nt] = anx[kk & 1][nt];
      if (kk < 5) {
        #pragma unroll
        for (int nt = 0; nt < 3; ++nt)
          anx[kk & 1][nt] = *(const uint4*)(wbase + nt * 16 * KP1 + (kk + 2) * 32);
      }
      s16x8 bm[8];
      if (kk < 6) {
        #pragma unroll
        for (int mt = 0; mt < 8; ++mt)
          bm[mt] = __builtin_bit_cast(s16x8,
                     *(const uint4*)(hbuf + (mt * 16 + lrow) * HROW + kk * 32 + lg * 8));
      } else {
        // channels 192..223 = [c0,c1,c2,1,0...]: only lanes lg==0 carry data
        #pragma unroll
        for (int mt = 0; mt < 8; ++mt) {
          uint4 t{0, 0, 0, 0};
          if (lg == 0) {
            const float* cp = crdL[mt * 16 + lrow];
            t.x = pk2bf(cp[0], cp[1]);
            t.y = pk2bf(cp[2], 1.0f);
          }
          bm[mt] = __builtin_bit_cast(s16x8, t);
        }
      }
      #pragma unroll
      for (int nt = 0; nt < 3; ++nt)
        #pragma unroll
        for (int mt = 0; mt < 8; ++mt)
          acc1[nt][mt] = __builtin_amdgcn_mfma_f32_16x16x32_bf16(
              __builtin_bit_cast(s16x8, acur[nt]), bm[mt], acc1[nt][mt], 0, 0, 0);
    }
  }
  __syncthreads();   // all gemm1 reads of hbuf done before h1 overwrite

  { // epilogue 1: gelu (b1 folded), h1 write: 4 consecutive cols per b64 store
    #pragma unroll
    for (int nt = 0; nt < 3; ++nt) {
      #pragma unroll
      for (int mt = 0; mt < 8; ++mt) {
        uint2 pk;
        pk.x = pk2bf(gelu_f(acc1[nt][mt][0]), gelu_f(acc1[nt][mt][1]));
        pk.y = pk2bf(gelu_f(acc1[nt][mt][2]), gelu_f(acc1[nt][mt][3]));
        *(uint2*)(hbuf + (mt * 16 + lrow) * HROW + ns * 48 + nt * 16 + lg * 4) = pk;
      }
    }
  }
  __syncthreads();

  // ---- gemm2 (normal orientation): D2 = h1-as-A x wT2-as-B, 2-deep prefetch
  f32x4 acc2[8][3] = {};
  {
    const uint16_t* w2base = wT2 + (size_t)(ns * 48 + lrow) * NH + lg * 8;
    uint4 bnx[2][3];
    #pragma unroll
    for (int nt = 0; nt < 3; ++nt) {
      bnx[0][nt] = *(const uint4*)(w2base + nt * 16 * NH);
      bnx[1][nt] = *(const uint4*)(w2base + nt * 16 * NH + 32);
    }
    #pragma unroll
    for (int kk = 0; kk < 6; ++kk) {
      uint4 bcur[3];
      #pragma unroll
      for (int nt = 0; nt < 3; ++nt) bcur[nt] = bnx[kk & 1][nt];
      if (kk < 4) {
        #pragma unroll
        for (int nt = 0; nt < 3; ++nt)
          bnx[kk & 1][nt] = *(const uint4*)(w2base + nt * 16 * NH + (kk + 2) * 32);
      }
      s16x8 am[8];
      #pragma unroll
      for (int mt = 0; mt < 8; ++mt)
        am[mt] = __builtin_bit_cast(s16x8,
                   *(const uint4*)(hbuf + (mt * 16 + lrow) * HROW + kk * 32 + lg * 8));
      #pragma unroll
      for (int mt = 0; mt < 8; ++mt)
        #pragma unroll
        for (int nt = 0; nt < 3; ++nt)
          acc2[mt][nt] = __builtin_amdgcn_mfma_f32_16x16x32_bf16(
              am[mt], __builtin_bit_cast(s16x8, bcur[nt]), acc2[mt][nt], 0, 0, 0);
    }
  }

  { // epilogue 2: mean over 16 rows of each C-tile (one supernode) + b2
    #pragma unroll
    for (int mt = 0; mt < 8; ++mt) {
      #pragma unroll
      for (int nt = 0; nt < 3; ++nt) {
        float ssum = acc2[mt][nt][0] + acc2[mt][nt][1] + acc2[mt][nt][2] + acc2[mt][nt][3];
        ssum += __shfl_xor(ssum, 16);
        ssum += __shfl_xor(ssum, 32);
        if (lane < 16) {
          int col = ns * 48 + nt * 16 + lrow;
          out[(size_t)(g * 8 + mt) * NH + col] = ssum * 0.0625f + b2v[col];
        }
      }
    }
  }
}

extern "C" void kernel_launch(void* const* d_in, const int* in_sizes, int n_in,
                              void* d_out, int out_size, void* d_ws, size_t ws_size,
                              hipStream_t stream) {
  (void)in_sizes; (void)n_in; (void)out_size; (void)ws_size;
  const float* pts  = (const float*)d_in[0];
  const int*   sidx = (const int*)d_in[1];
  const float* w_in = (const float*)d_in[2];
  const float* b_in = (const float*)d_in[3];
  const float* w1   = (const float*)d_in[4];
  const float* b1   = (const float*)d_in[5];
  const float* w2   = (const float*)d_in[6];
  const float* b2   = (const float*)d_in[7];
  float* out = (float*)d_out;

  u64* keys = (u64*)d_ws;                                       // 8192*64*8 = 4 MB
  uint16_t* wT1e = (uint16_t*)((char*)d_ws + (size_t)NB * NS * 64 * 8);
  uint16_t* wT2  = wT1e + NH * KP1;

  hipLaunchKernelGGL(prep_weights, dim3(NH), dim3(64), 0, stream,
                     w_in, b_in, w1, b1, w2, wT1e, wT2);

  hipLaunchKernelGGL(knn_kernel, dim3(NB * 128), dim3(512), 0, stream,
                     pts, sidx, keys);

  hipLaunchKernelGGL(mlp_kernel, dim3(NB * NS / 8), dim3(256), 0, stream,
                     pts, keys, b2, wT1e, wT2, out);
}

// Round 13
// 91.543 us; speedup vs baseline: 1.1008x; 1.0065x over previous
//
#include <hip/hip_runtime.h>
#include <stdint.h>

#define NB   8
#define NPTS 8192
#define NS   1024
#define NK   16
#define NH   192
#define KP1  224   // extended K for gemm1 weights: 192 + 3 coords + 1 bias + 28 zero pad
#define HROW 196   // hbuf row stride (bf16): 98 dw, gcd(98,32)=2 -> 16-distinct banks/16 rows
#define QTR  2048  // points per knn quarter-block

typedef float    f32x4 __attribute__((ext_vector_type(4)));
typedef short    s16x8 __attribute__((ext_vector_type(8)));
typedef uint32_t u32;
typedef unsigned long long u64;

constexpr float OMEGA[32] = {
  1.0f, 0.74989420933245585f, 0.56234132519034907f, 0.42169650342858223f,
  0.31622776601683794f, 0.23713737056616552f, 0.17782794100389229f, 0.13335214321633237f,
  0.1f, 0.074989420933245585f, 0.056234132519034907f, 0.042169650342858223f,
  0.031622776601683794f, 0.023713737056616552f, 0.017782794100389229f, 0.013335214321633237f,
  0.01f, 0.0074989420933245585f, 0.0056234132519034907f, 0.0042169650342858223f,
  0.0031622776601683794f, 0.0023713737056616552f, 0.0017782794100389229f, 0.0013335214321633237f,
  0.001f, 0.00074989420933245585f, 0.00056234132519034907f, 0.00042169650342858223f,
  0.00031622776601683794f, 0.00023713737056616552f, 0.00017782794100389229f, 0.00013335214321633237f };

__device__ __forceinline__ uint16_t f2bf(float f) {
  u32 u = __float_as_uint(f);
  return (uint16_t)((u + 0x7FFFu + ((u >> 16) & 1u)) >> 16);
}
__device__ __forceinline__ u32 pk2bf(float f0, float f1) {
  return ((__float_as_uint(f0) + 0x8000u) >> 16) |
         ((__float_as_uint(f1) + 0x8000u) & 0xFFFF0000u);
}

// ---------------- kernel A: build extended transposed weights ----------------
__global__ void __launch_bounds__(64) prep_weights(
    const float* __restrict__ w_in, const float* __restrict__ b_in,
    const float* __restrict__ w1, const float* __restrict__ b1,
    const float* __restrict__ w2,
    uint16_t* __restrict__ wT1e, uint16_t* __restrict__ wT2) {
  const int n = blockIdx.x, t = threadIdx.x;
  float p0 = 0, p1 = 0, p2 = 0, pb = 0;
  #pragma unroll
  for (int kk = 0; kk < 3; ++kk) {
    int c = kk * 64 + t;
    float w1cn = w1[c * NH + n];
    wT1e[n * KP1 + c] = f2bf(w1cn);
    wT2 [n * NH  + c] = f2bf(w2[c * NH + n]);
    p0 = fmaf(w_in[0 * NH + c], w1cn, p0);
    p1 = fmaf(w_in[1 * NH + c], w1cn, p1);
    p2 = fmaf(w_in[2 * NH + c], w1cn, p2);
    pb = fmaf(b_in[c], w1cn, pb);
  }
  #pragma unroll
  for (int off = 32; off; off >>= 1) {
    p0 += __shfl_down(p0, off);
    p1 += __shfl_down(p1, off);
    p2 += __shfl_down(p2, off);
    pb += __shfl_down(pb, off);
  }
  if (t == 0) {
    wT1e[n * KP1 + 192] = f2bf(p0);
    wT1e[n * KP1 + 193] = f2bf(p1);
    wT1e[n * KP1 + 194] = f2bf(p2);
    wT1e[n * KP1 + 195] = f2bf(pb + b1[n]);
  }
  if (t >= 4 && t < 32) wT1e[n * KP1 + 192 + t] = 0;
}

// ---------------- kernel B: exact top-16 over a QUARTER ----------------
// r13 diet: (1) pass-1 tracks minT (loop counter, SGPR) instead of global idx
// -> drops a v_add per candidate in BOTH passes (cndmask/cmp take the SGPR
// operand directly); global idx reconstructed once pre-sort and only inside
// the rare insert branch. (2) float4-packed points: 1 ds_read_b128/candidate.
// Key = (bits(d)<<32)|idx: exact (dist,idx) stable-top_k semantics unchanged.
__global__ void __launch_bounds__(512, 8) knn_kernel(const float* __restrict__ pts,
                                                     const int* __restrict__ sidx,
                                                     u64* __restrict__ keys) {
  __shared__ float4 P4[QTR];   // 32 KB (x,y,z,pad) -> still 4 blocks/CU (grid-capped)
  const int bid = blockIdx.x;
  const int b = bid >> 7;
  const int chunk = (bid >> 2) & 31;
  const int quarter = bid & 3;
  const int pbase = quarter * QTR;
  const float* pb = pts + ((size_t)b * NPTS + pbase) * 3;
  for (int i = threadIdx.x; i < QTR; i += 512)
    P4[i] = float4{pb[3 * i], pb[3 * i + 1], pb[3 * i + 2], 0.0f};
  __syncthreads();
  const int wave = threadIdx.x >> 6, lane = threadIdx.x & 63;
  const int sbase = chunk * 32 + wave * 4;

  float sx[4], sy[4], sz[4], minD[4], Td[4];
  u32 minT[4];
  u64 arr[4], T[4];
  #pragma unroll
  for (int q = 0; q < 4; ++q) {
    int si = sidx[b * NS + sbase + q];
    const float* qp = pts + ((size_t)b * NPTS + si) * 3;   // L2 broadcast
    sx[q] = qp[0]; sy[q] = qp[1]; sz[q] = qp[2];
    minD[q] = __uint_as_float(0x7F800000u);
    minT[q] = 0xFFFFFFFFu;
  }

  // ---- pass 1: lane-private minimum; track iteration number only
  for (int t = 0; t < QTR / 64; ++t) {
    float4 p = P4[t * 64 + lane];
    #pragma unroll
    for (int q = 0; q < 4; ++q) {
      float dx = p.x - sx[q], dy = p.y - sy[q], dz = p.z - sz[q];
      float d = __fadd_rn(__fadd_rn(__fmul_rn(dx, dx), __fmul_rn(dy, dy)),
                          __fmul_rn(dz, dz));
      bool c = d < minD[q];            // strict: keeps lowest idx on exact ties
      minD[q] = c ? d : minD[q];
      minT[q] = c ? (u32)t : minT[q];  // SGPR src -> no per-iter idx add
    }
  }

  // ---- reconstruct keys, bitonic sort of the 64 per-lane minima
  #pragma unroll
  for (int q = 0; q < 4; ++q) {
    u32 gidx = (u32)(pbase + (int)minT[q] * 64 + lane);
    u64 key = ((u64)__float_as_uint(minD[q]) << 32) | gidx;
    #pragma unroll
    for (int k = 2; k <= 64; k <<= 1) {
      #pragma unroll
      for (int jj = k >> 1; jj > 0; jj >>= 1) {
        u64 p = __shfl_xor(key, jj);
        bool takeMin = (((lane & jj) == 0) == ((lane & k) == 0));
        key = (takeMin == (p < key)) ? p : key;
      }
    }
    arr[q] = (lane < 16) ? key : ~0ull;
    T[q] = __shfl(key, 15);                  // upper bound on true 16th key
    Td[q] = __uint_as_float((u32)(T[q] >> 32));
  }

  // ---- pass 2: exact insertion of the few candidates below the threshold
  for (int t = 0; t < QTR / 64; ++t) {
    float4 p = P4[t * 64 + lane];
    #pragma unroll
    for (int q = 0; q < 4; ++q) {
      float dx = p.x - sx[q], dy = p.y - sy[q], dz = p.z - sz[q];
      float d = __fadd_rn(__fadd_rn(__fmul_rn(dx, dx), __fmul_rn(dy, dy)),
                          __fmul_rn(dz, dz));
      // d<=Td superset test; own pass-1 argmin excluded via scalar-t compare
      u64 ball = __ballot(d <= Td[q] && minT[q] != (u32)t);
      if (ball) {                              // wave-uniform, rare
        u64 key = ((u64)__float_as_uint(d) << 32) | (u32)(pbase + t * 64 + lane);
        do {
          int src = __builtin_ctzll(ball);
          ball &= ball - 1;
          u64 k2 = __shfl(key, src);
          if (k2 < T[q]) {                     // exact (dist,idx) compare
            int r = __popcll(__ballot(arr[q] < k2));
            u64 up = __shfl_up(arr[q], 1);
            if (lane == r) arr[q] = k2;
            else if (lane > r && lane < 16) arr[q] = up;
            T[q] = __shfl(arr[q], 15);
            Td[q] = __uint_as_float((u32)(T[q] >> 32));
          }
        } while (ball);
      }
    }
  }
  #pragma unroll
  for (int q = 0; q < 4; ++q)
    if (lane < 16)
      keys[((size_t)(b * NS + sbase + q)) * 64 + quarter * 16 + lane] = arr[q];
}

// ---------------- kernel C: merge + gather + embed + MLP + mean-pool (r12, unchanged) ----
__device__ __forceinline__ float h0ch(int c, float c0, float c1, float c2) {
  int dd = c >> 6, i = c & 63, m = i & 31;
  float coord = (dd == 0) ? c0 : ((dd == 1) ? c1 : c2);
  float arg = coord * OMEGA[m];
  return (i < 32) ? __sinf(arg) : __cosf(arg);
}

__device__ __forceinline__ float gelu_f(float x) {
  float v = -1.5957691216057308f * __fmaf_rn(0.044715f * x, x * x, x);
  return x * __builtin_amdgcn_rcpf(1.0f + __expf(v));
}

__global__ void __launch_bounds__(256, 3) mlp_kernel(
    const float* __restrict__ pts, const u64* __restrict__ keys,
    const float* __restrict__ b2v,
    const uint16_t* __restrict__ wT1e, const uint16_t* __restrict__ wT2,
    float* __restrict__ out) {
  __shared__ uint16_t hbuf[128 * HROW];   // 50.2 KB
  __shared__ float crdL[128][3];          // 1.5 KB (coords per row, for kk6 frag)
  __shared__ int nbrL[128];               // 0.5 KB  -> total 52.2 KB: 3 blocks/CU
  const int g = blockIdx.x, tid = threadIdx.x;
  const int wave = tid >> 6, lane = tid & 63;
  const int lrow = lane & 15, lg = lane >> 4;
  const int ns = wave;                    // n-slice: cols ns*48..+48

  #pragma unroll
  for (int ii = 0; ii < 2; ++ii) { // merge 4 sorted 16-lists for query g*8 + ii*4 + wave
    int q = ii * 4 + wave;
    int list = lane >> 4, pos = lane & 15;
    int rpos = (list & 1) ? (15 - pos) : pos;
    u64 key = keys[((size_t)g * 8 + q) * 64 + list * 16 + rpos];
    #pragma unroll
    for (int jj = 16; jj > 0; jj >>= 1) {
      u64 p = __shfl_xor(key, jj);
      bool takeMin = (((lane & jj) == 0) == ((lane & 32) == 0));
      key = (takeMin == (p < key)) ? p : key;
    }
    #pragma unroll
    for (int jj = 32; jj > 0; jj >>= 1) {
      u64 p = __shfl_xor(key, jj);
      bool takeMin = ((lane & jj) == 0);
      key = (takeMin == (p < key)) ? p : key;
    }
    if (lane < 16) nbrL[q * 16 + lane] = (int)(u32)key;
  }
  __syncthreads();

  { // h0 fill (sincos channels 0..191), 2 threads/row, static half-loops
    int r = tid >> 1, half = tid & 1;
    int grow = g * 128 + r;
    int b = grow >> 14;
    int pidx = nbrL[r];
    const float* pp = pts + ((size_t)b * NPTS + pidx) * 3;
    float c0 = pp[0], c1 = pp[1], c2 = pp[2];
    uint16_t* hrow = hbuf + r * HROW;
    if (half == 0) {
      crdL[r][0] = c0; crdL[r][1] = c1; crdL[r][2] = c2;
      #pragma unroll
      for (int jj = 0; jj < 24; ++jj) {
        const int c = jj * 4;
        uint2 pk;
        pk.x = pk2bf(h0ch(c,     c0, c1, c2), h0ch(c + 1, c0, c1, c2));
        pk.y = pk2bf(h0ch(c + 2, c0, c1, c2), h0ch(c + 3, c0, c1, c2));
        *(uint2*)(hrow + c) = pk;
      }
    } else {
      #pragma unroll
      for (int jj = 0; jj < 24; ++jj) {
        const int c = 96 + jj * 4;
        uint2 pk;
        pk.x = pk2bf(h0ch(c,     c0, c1, c2), h0ch(c + 1, c0, c1, c2));
        pk.y = pk2bf(h0ch(c + 2, c0, c1, c2), h0ch(c + 3, c0, c1, c2));
        *(uint2*)(hrow + c) = pk;
      }
    }
  }
  __syncthreads();

  // ---- gemm1 (SWAPPED operands): D1^T = wT1e-as-A x h0-as-B; kk6 B built in-reg
  f32x4 acc1[3][8] = {};
  {
    const uint16_t* wbase = wT1e + (size_t)(ns * 48 + lrow) * KP1 + lg * 8;
    uint4 anx[2][3];
    #pragma unroll
    for (int nt = 0; nt < 3; ++nt) {
      anx[0][nt] = *(const uint4*)(wbase + nt * 16 * KP1);
      anx[1][nt] = *(const uint4*)(wbase + nt * 16 * KP1 + 32);
    }
    #pragma unroll
    for (int kk = 0; kk < 7; ++kk) {
      uint4 acur[3];
      #pragma unroll
      for (int nt = 0; nt < 3; ++nt) acur[nt] = anx[kk & 1][nt];
      if (kk < 5) {
        #pragma unroll
        for (int nt = 0; nt < 3; ++nt)
          anx[kk & 1][nt] = *(const uint4*)(wbase + nt * 16 * KP1 + (kk + 2) * 32);
      }
      s16x8 bm[8];
      if (kk < 6) {
        #pragma unroll
        for (int mt = 0; mt < 8; ++mt)
          bm[mt] = __builtin_bit_cast(s16x8,
                     *(const uint4*)(hbuf + (mt * 16 + lrow) * HROW + kk * 32 + lg * 8));
      } else {
        // channels 192..223 = [c0,c1,c2,1,0...]: only lanes lg==0 carry data
        #pragma unroll
        for (int mt = 0; mt < 8; ++mt) {
          uint4 t{0, 0, 0, 0};
          if (lg == 0) {
            const float* cp = crdL[mt * 16 + lrow];
            t.x = pk2bf(cp[0], cp[1]);
            t.y = pk2bf(cp[2], 1.0f);
          }
          bm[mt] = __builtin_bit_cast(s16x8, t);
        }
      }
      #pragma unroll
      for (int nt = 0; nt < 3; ++nt)
        #pragma unroll
        for (int mt = 0; mt < 8; ++mt)
          acc1[nt][mt] = __builtin_amdgcn_mfma_f32_16x16x32_bf16(
              __builtin_bit_cast(s16x8, acur[nt]), bm[mt], acc1[nt][mt], 0, 0, 0);
    }
  }
  __syncthreads();   // all gemm1 reads of hbuf done before h1 overwrite

  { // epilogue 1: gelu (b1 folded), h1 write: 4 consecutive cols per b64 store
    #pragma unroll
    for (int nt = 0; nt < 3; ++nt) {
      #pragma unroll
      for (int mt = 0; mt < 8; ++mt) {
        uint2 pk;
        pk.x = pk2bf(gelu_f(acc1[nt][mt][0]), gelu_f(acc1[nt][mt][1]));
        pk.y = pk2bf(gelu_f(acc1[nt][mt][2]), gelu_f(acc1[nt][mt][3]));
        *(uint2*)(hbuf + (mt * 16 + lrow) * HROW + ns * 48 + nt * 16 + lg * 4) = pk;
      }
    }
  }
  __syncthreads();

  // ---- gemm2 (normal orientation): D2 = h1-as-A x wT2-as-B, 2-deep prefetch
  f32x4 acc2[8][3] = {};
  {
    const uint16_t* w2base = wT2 + (size_t)(ns * 48 + lrow) * NH + lg * 8;
    uint4 bnx[2][3];
    #pragma unroll
    for (int nt = 0; nt < 3; ++nt) {
      bnx[0][nt] = *(const uint4*)(w2base + nt * 16 * NH);
      bnx[1][nt] = *(const uint4*)(w2base + nt * 16 * NH + 32);
    }
    #pragma unroll
    for (int kk = 0; kk < 6; ++kk) {
      uint4 bcur[3];
      #pragma unroll
      for (int nt = 0; nt < 3; ++nt) bcur[nt] = bnx[kk & 1][nt];
      if (kk < 4) {
        #pragma unroll
        for (int nt = 0; nt < 3; ++nt)
          bnx[kk & 1][nt] = *(const uint4*)(w2base + nt * 16 * NH + (kk + 2) * 32);
      }
      s16x8 am[8];
      #pragma unroll
      for (int mt = 0; mt < 8; ++mt)
        am[mt] = __builtin_bit_cast(s16x8,
                   *(const uint4*)(hbuf + (mt * 16 + lrow) * HROW + kk * 32 + lg * 8));
      #pragma unroll
      for (int mt = 0; mt < 8; ++mt)
        #pragma unroll
        for (int nt = 0; nt < 3; ++nt)
          acc2[mt][nt] = __builtin_amdgcn_mfma_f32_16x16x32_bf16(
              am[mt], __builtin_bit_cast(s16x8, bcur[nt]), acc2[mt][nt], 0, 0, 0);
    }
  }

  { // epilogue 2: mean over 16 rows of each C-tile (one supernode) + b2
    #pragma unroll
    for (int mt = 0; mt < 8; ++mt) {
      #pragma unroll
      for (int nt = 0; nt < 3; ++nt) {
        float ssum = acc2[mt][nt][0] + acc2[mt][nt][1] + acc2[mt][nt][2] + acc2[mt][nt][3];
        ssum += __shfl_xor(ssum, 16);
        ssum += __shfl_xor(ssum, 32);
        if (lane < 16) {
          int col = ns * 48 + nt * 16 + lrow;
          out[(size_t)(g * 8 + mt) * NH + col] = ssum * 0.0625f + b2v[col];
        }
      }
    }
  }
}

extern "C" void kernel_launch(void* const* d_in, const int* in_sizes, int n_in,
                              void* d_out, int out_size, void* d_ws, size_t ws_size,
                              hipStream_t stream) {
  (void)in_sizes; (void)n_in; (void)out_size; (void)ws_size;
  const float* pts  = (const float*)d_in[0];
  const int*   sidx = (const int*)d_in[1];
  const float* w_in = (const float*)d_in[2];
  const float* b_in = (const float*)d_in[3];
  const float* w1   = (const float*)d_in[4];
  const float* b1   = (const float*)d_in[5];
  const float* w2   = (const float*)d_in[6];
  const float* b2   = (const float*)d_in[7];
  float* out = (float*)d_out;

  u64* keys = (u64*)d_ws;                                       // 8192*64*8 = 4 MB
  uint16_t* wT1e = (uint16_t*)((char*)d_ws + (size_t)NB * NS * 64 * 8);
  uint16_t* wT2  = wT1e + NH * KP1;

  hipLaunchKernelGGL(prep_weights, dim3(NH), dim3(64), 0, stream,
                     w_in, b_in, w1, b1, w2, wT1e, wT2);

  hipLaunchKernelGGL(knn_kernel, dim3(NB * 128), dim3(512), 0, stream,
                     pts, sidx, keys);

  hipLaunchKernelGGL(mlp_kernel, dim3(NB * NS / 8), dim3(256), 0, stream,
                     pts, keys, b2, wT1e, wT2, out);
}